// Round 4
// baseline (558.463 us; speedup 1.0000x reference)
//
#include <hip/hip_runtime.h>
#include <hip/hip_bf16.h>

// RGCN 2-layer forward, gather formulation, wave-per-dst.
// sniff -> rank/hist (atomic returns rank) -> 3-kernel scan -> atomic-free
// scatter -> l1 (wave/dst: 4 edges x 16 feat, reg acc) ->
// l2 (wave/dst: per-relation sums in LDS via ds_add_f32, then
//     out = sum_r inv[r]*(s_r @ w2[r]) + x@root2 + b2, log-softmax, butterfly).

constexpr int Nn = 50000;
constexpr int Hh = 16;
constexpr int Rr = 32;
constexpr int Cc = 8;
constexpr int Ee = 1600000;
constexpr int NBLK = (Nn + 255) / 256;   // 196

__device__ __forceinline__ float b2f(__hip_bfloat16 v) { return __bfloat162float(v); }

// --- 0. dtype sniff (bf16 vs fp32 delivery) -----------------------------------
__global__ void sniff_kernel(const unsigned short* __restrict__ w, int* __restrict__ flag) {
    if (blockIdx.x == 0 && threadIdx.x == 0) {
        int hits = 0;
        for (int i = 0; i < 64; ++i) {
            unsigned short u = w[2 * i];
            int e = (u >> 7) & 0xFF;
            if (e >= 100 && e <= 130) ++hits;
        }
        *flag = (hits >= 32) ? 1 : 0;   // 1 = bf16, 0 = fp32
    }
}

// --- 1. degree histogram; atomic's return value IS the edge's rank ------------
__global__ void rank_kernel(const int* __restrict__ dst, int* __restrict__ deg,
                            int* __restrict__ rank) {
    int e = blockIdx.x * blockDim.x + threadIdx.x;
    if (e < Ee) rank[e] = atomicAdd(&deg[dst[e]], 1);
}

// --- 2a. per-block exclusive scan + block sums --------------------------------
__global__ __launch_bounds__(256) void scan1_kernel(const int* __restrict__ deg,
                                                    int* __restrict__ offs,
                                                    int* __restrict__ bsum) {
    __shared__ int lsum[4];
    int tid = threadIdx.x, lane = tid & 63, w = tid >> 6;
    int i = blockIdx.x * 256 + tid;
    int v = (i < Nn) ? deg[i] : 0;
    int s = v;
#pragma unroll
    for (int o = 1; o < 64; o <<= 1) { int t = __shfl_up(s, o, 64); if (lane >= o) s += t; }
    if (lane == 63) lsum[w] = s;
    __syncthreads();
    int base = 0;
    for (int j = 0; j < w; ++j) base += lsum[j];
    int excl = base + s - v;
    if (i < Nn) offs[i] = excl;
    if (tid == 255) bsum[blockIdx.x] = excl + v;
}

// --- 2b. scan the NBLK (<=256) block sums; write grand total to offs[Nn] ------
__global__ __launch_bounds__(256) void scan2_kernel(const int* __restrict__ bsum,
                                                    int* __restrict__ carry,
                                                    int* __restrict__ offs) {
    __shared__ int lsum[4];
    int tid = threadIdx.x, lane = tid & 63, w = tid >> 6;
    int v = (tid < NBLK) ? bsum[tid] : 0;
    int s = v;
#pragma unroll
    for (int o = 1; o < 64; o <<= 1) { int t = __shfl_up(s, o, 64); if (lane >= o) s += t; }
    if (lane == 63) lsum[w] = s;
    __syncthreads();
    int base = 0;
    for (int j = 0; j < w; ++j) base += lsum[j];
    int excl = base + s - v;
    if (tid < NBLK) carry[tid] = excl;
    if (tid == 255) offs[Nn] = excl;   // v==0 here -> excl == grand total
}

// --- 2c. add carries ----------------------------------------------------------
__global__ void scan3_kernel(int* __restrict__ offs, const int* __restrict__ carry) {
    int i = blockIdx.x * 256 + threadIdx.x;
    if (i < Nn) offs[i] += carry[blockIdx.x];
}

// --- 3. atomic-free scatter into dst-sorted order, packed src | rel<<16 -------
__global__ void scatter_kernel(const int* __restrict__ src, const int* __restrict__ dst,
                               const int* __restrict__ et, const int* __restrict__ offs,
                               const int* __restrict__ rank, unsigned int* __restrict__ sorted) {
    int e = blockIdx.x * blockDim.x + threadIdx.x;
    if (e < Ee)
        sorted[offs[dst[e]] + rank[e]] = (unsigned)src[e] | ((unsigned)et[e] << 16);
}

// --- 4. layer 1: one wave per dst, 4 edges x 16 features, zero atomics --------
__global__ __launch_bounds__(256) void l1_kernel(const unsigned int* __restrict__ sorted,
                                                 const int* __restrict__ offs,
                                                 const void* __restrict__ w1,
                                                 const void* __restrict__ root1,
                                                 const void* __restrict__ b1,
                                                 const int* __restrict__ flag,
                                                 float* __restrict__ x) {
    __shared__ int   hist[4 * 32];
    __shared__ float invh[4 * 32];
    int tid = threadIdx.x, w = tid >> 6, lane = tid & 63;
    int ep = lane >> 4, h = lane & 15;
    int d = blockIdx.x * 4 + w;                  // 12500*4 == Nn exactly
    if (lane < 32) hist[w * 32 + lane] = 0;
    __syncthreads();
    int off = offs[d], deg = offs[d + 1] - off;
    for (int i = lane; i < deg; i += 64)
        atomicAdd(&hist[w * 32 + (sorted[off + i] >> 16)], 1);
    __syncthreads();
    if (lane < 32) {
        int c = hist[w * 32 + lane];
        invh[w * 32 + lane] = c ? 1.0f / (float)c : 0.0f;
    }
    __syncthreads();
    float acc = 0.0f;
    int isbf = *flag;
    if (isbf) {
        const __hip_bfloat16* W = (const __hip_bfloat16*)w1;
#pragma unroll 2
        for (int i = ep; i < deg; i += 4) {
            unsigned p = sorted[off + i];
            int rel = p >> 16, sN = p & 0xFFFF;
            acc += b2f(W[(size_t)(rel * Nn + sN) * Hh + h]) * invh[w * 32 + rel];
        }
    } else {
        const float* W = (const float*)w1;
#pragma unroll 2
        for (int i = ep; i < deg; i += 4) {
            unsigned p = sorted[off + i];
            int rel = p >> 16, sN = p & 0xFFFF;
            acc += W[(size_t)(rel * Nn + sN) * Hh + h] * invh[w * 32 + rel];
        }
    }
    acc += __shfl_xor(acc, 16, 64);
    acc += __shfl_xor(acc, 32, 64);
    if (ep == 0) {
        float r1, bb;
        if (isbf) {
            r1 = b2f(((const __hip_bfloat16*)root1)[d * Hh + h]);
            bb = b2f(((const __hip_bfloat16*)b1)[h]);
        } else {
            r1 = ((const float*)root1)[d * Hh + h];
            bb = ((const float*)b1)[h];
        }
        float v = acc + r1 + bb;
        x[d * Hh + h] = v > 0.0f ? v : 0.0f;
    }
}

// --- 5. layer 2 + epilogue: one wave per dst ----------------------------------
// Phase A: s[r][h] += x[src][h] via ds_add_f32 (4 edges parallel).
// Phase B: lane=(r,half): pl[c] = inv[r]*sum_h s[r][h]*w2[r][h][c]; lanes r==0
// add the x[d]@root2 half-partials; 64-lane butterfly; +b2; log-softmax; store.
__global__ __launch_bounds__(256) void l2_kernel(const unsigned int* __restrict__ sorted,
                                                 const int* __restrict__ offs,
                                                 const float* __restrict__ x,
                                                 const void* __restrict__ w2,
                                                 const void* __restrict__ root2,
                                                 const void* __restrict__ b2v,
                                                 const int* __restrict__ flag,
                                                 void* __restrict__ out) {
    __shared__ float smem[4 * 544];              // s[r][h], stride 17 (bank spread)
    __shared__ int   hist[4 * 32];
    __shared__ float invh[4 * 32];
    int tid = threadIdx.x, w = tid >> 6, lane = tid & 63;
    int ep = lane >> 4, h = lane & 15;
    int d = blockIdx.x * 4 + w;
    for (int k = lane; k < 544; k += 64) smem[w * 544 + k] = 0.0f;
    if (lane < 32) hist[w * 32 + lane] = 0;
    __syncthreads();
    int off = offs[d], deg = offs[d + 1] - off;
#pragma unroll 2
    for (int i0 = 0; i0 < deg; i0 += 4) {
        int i = i0 + ep;
        if (i < deg) {
            unsigned p = sorted[off + i];
            int rel = p >> 16, sN = p & 0xFFFF;
            float xv = x[(size_t)sN * Hh + h];
            atomicAdd(&smem[w * 544 + rel * 17 + h], xv);
            if (h == 0) atomicAdd(&hist[w * 32 + rel], 1);
        }
    }
    __syncthreads();
    if (lane < 32) {
        int c = hist[w * 32 + lane];
        invh[w * 32 + lane] = c ? 1.0f / (float)c : 0.0f;
    }
    __syncthreads();
    int r = lane >> 1, half = lane & 1, hbase = half * 8;
    int isbf = *flag;
    float pl[8];
#pragma unroll
    for (int c = 0; c < 8; ++c) pl[c] = 0.0f;
    if (isbf) {
        const __hip_bfloat16* W = (const __hip_bfloat16*)w2 + (size_t)(r * Hh + hbase) * Cc;
#pragma unroll
        for (int hh = 0; hh < 8; ++hh) {
            float sv = smem[w * 544 + r * 17 + hbase + hh];
            const __hip_bfloat162* wp = (const __hip_bfloat162*)(W + hh * Cc);
#pragma unroll
            for (int q = 0; q < 4; ++q) {
                __hip_bfloat162 bv = wp[q];
                pl[q * 2 + 0] += sv * __low2float(bv);
                pl[q * 2 + 1] += sv * __high2float(bv);
            }
        }
    } else {
        const float* W = (const float*)w2 + (size_t)(r * Hh + hbase) * Cc;
#pragma unroll
        for (int hh = 0; hh < 8; ++hh) {
            float sv = smem[w * 544 + r * 17 + hbase + hh];
            const float4* wp = (const float4*)(W + hh * Cc);
            float4 a = wp[0], b = wp[1];
            pl[0] += sv * a.x; pl[1] += sv * a.y; pl[2] += sv * a.z; pl[3] += sv * a.w;
            pl[4] += sv * b.x; pl[5] += sv * b.y; pl[6] += sv * b.z; pl[7] += sv * b.w;
        }
    }
    float inv = invh[w * 32 + r];
#pragma unroll
    for (int c = 0; c < 8; ++c) pl[c] *= inv;
    if (r == 0) {   // self-loop (root2) contribution, split across the 2 halves
        if (isbf) {
#pragma unroll
            for (int hh = 0; hh < 8; ++hh) {
                float xv = x[(size_t)d * Hh + hbase + hh];
                const __hip_bfloat162* rp =
                    (const __hip_bfloat162*)((const __hip_bfloat16*)root2 + (hbase + hh) * Cc);
#pragma unroll
                for (int q = 0; q < 4; ++q) {
                    __hip_bfloat162 bv = rp[q];
                    pl[q * 2 + 0] += xv * __low2float(bv);
                    pl[q * 2 + 1] += xv * __high2float(bv);
                }
            }
        } else {
#pragma unroll
            for (int hh = 0; hh < 8; ++hh) {
                float xv = x[(size_t)d * Hh + hbase + hh];
                const float4* rp = (const float4*)((const float*)root2 + (hbase + hh) * Cc);
                float4 a = rp[0], b = rp[1];
                pl[0] += xv * a.x; pl[1] += xv * a.y; pl[2] += xv * a.z; pl[3] += xv * a.w;
                pl[4] += xv * b.x; pl[5] += xv * b.y; pl[6] += xv * b.z; pl[7] += xv * b.w;
            }
        }
    }
#pragma unroll
    for (int o = 1; o < 64; o <<= 1) {
#pragma unroll
        for (int c = 0; c < 8; ++c) pl[c] += __shfl_xor(pl[c], o, 64);
    }
#pragma unroll
    for (int c = 0; c < 8; ++c)
        pl[c] += isbf ? b2f(((const __hip_bfloat16*)b2v)[c]) : ((const float*)b2v)[c];
    float m = pl[0];
#pragma unroll
    for (int c = 1; c < 8; ++c) m = fmaxf(m, pl[c]);
    float ssum = 0.0f;
#pragma unroll
    for (int c = 0; c < 8; ++c) ssum += expf(pl[c] - m);
    float lse = m + logf(ssum);
    if (lane == 0) {
        if (isbf) {
            union { unsigned short us[8]; uint4 v4; } o;
#pragma unroll
            for (int c = 0; c < 8; ++c) {
                __hip_bfloat16 b = __float2bfloat16(pl[c] - lse);
                o.us[c] = *(unsigned short*)&b;
            }
            *(uint4*)((__hip_bfloat16*)out + (size_t)d * Cc) = o.v4;
        } else {
            float* op = (float*)out + (size_t)d * Cc;
            ((float4*)op)[0] = make_float4(pl[0] - lse, pl[1] - lse, pl[2] - lse, pl[3] - lse);
            ((float4*)op)[1] = make_float4(pl[4] - lse, pl[5] - lse, pl[6] - lse, pl[7] - lse);
        }
    }
}

extern "C" void kernel_launch(void* const* d_in, const int* in_sizes, int n_in,
                              void* d_out, int out_size, void* d_ws, size_t ws_size,
                              hipStream_t stream) {
    const int* edge_index = (const int*)d_in[0];     // [2, E]
    const int* src = edge_index;
    const int* dst = edge_index + Ee;
    const int* et  = (const int*)d_in[1];            // [E]
    const void* w1    = d_in[2];  // [R,N,H]
    const void* root1 = d_in[3];  // [N,H]
    const void* b1    = d_in[4];  // [H]
    const void* w2    = d_in[5];  // [R,H,C]
    const void* root2 = d_in[6];  // [H,C]
    const void* b2    = d_in[7];  // [C]

    // ws (4B words): deg[Nn] | rank[Ee] | offs[Nn+4] | bsum[256] | carry[256] |
    //                sorted[Ee] | x[Nn*Hh] | flag[1]   (~16.4 MB)
    int* deg   = (int*)d_ws;
    int* rank  = deg + Nn;
    int* offs  = rank + Ee;
    int* bsum  = offs + Nn + 4;
    int* carry = bsum + 256;
    unsigned int* sorted = (unsigned int*)(carry + 256);
    float* x   = (float*)(sorted + Ee);
    int* flag  = (int*)(x + (size_t)Nn * Hh);

    hipMemsetAsync(deg, 0, (size_t)Nn * sizeof(int), stream);

    sniff_kernel<<<1, 64, 0, stream>>>((const unsigned short*)w1, flag);
    rank_kernel<<<(Ee + 255) / 256, 256, 0, stream>>>(dst, deg, rank);
    scan1_kernel<<<NBLK, 256, 0, stream>>>(deg, offs, bsum);
    scan2_kernel<<<1, 256, 0, stream>>>(bsum, carry, offs);
    scan3_kernel<<<NBLK, 256, 0, stream>>>(offs, carry);
    scatter_kernel<<<(Ee + 255) / 256, 256, 0, stream>>>(src, dst, et, offs, rank, sorted);
    l1_kernel<<<Nn / 4, 256, 0, stream>>>(sorted, offs, w1, root1, b1, flag, x);
    l2_kernel<<<Nn / 4, 256, 0, stream>>>(sorted, offs, x, w2, root2, b2, flag, d_out);
}